// Round 1
// baseline (1711.559 us; speedup 1.0000x reference)
//
#include <hip/hip_runtime.h>
#include <hip/hip_bf16.h>

// Problem constants
#define B_TOT 32768
#define C_CH  128
#define NPOS  12
#define HID_N 200
#define K1    1280   // (12-3+1)*128

// Workspace byte offsets
#define OFF_G    0u        // bf16 [128][128]  G[a][c] = sum_o wq[o,a]*wk[o,c]
#define OFF_WVT  32768u    // bf16 [128][128]  WvT[j][c] = wv[c][j]
#define OFF_RT   65536u    // f32  [12][128]   R[i][c] = sum_o bq[o]wk[o,c] + wq[o,c]*pos[o,i]
#define OFF_BNS  71680u    // f32  [128]       gamma*rsqrt(var+eps)
#define OFF_BNB  72192u    // f32  [128]       beta - mean*inv
#define OFF_W1T  72704u    // bf16 [1280][200] fc1_w transposed
#define OFF_P    589824u   // bf16 [32768][1280] pooled activations

static __device__ __forceinline__ float bf2f(__hip_bfloat16 h) { return __bfloat162float(h); }

// ---------------------------------------------------------------- setup ----
__global__ void setup_kernel(const float* __restrict__ wq, const float* __restrict__ bq,
                             const float* __restrict__ wk,
                             const float* __restrict__ rel_h, const float* __restrict__ rel_w,
                             const float* __restrict__ wv,
                             const float* __restrict__ gamma, const float* __restrict__ beta,
                             const float* __restrict__ mean, const float* __restrict__ var,
                             const float* __restrict__ fc1w,
                             char* __restrict__ ws)
{
    __hip_bfloat16* G   = (__hip_bfloat16*)(ws + OFF_G);
    __hip_bfloat16* WvT = (__hip_bfloat16*)(ws + OFF_WVT);
    float*          Rt  = (float*)(ws + OFF_RT);
    float*          BnS = (float*)(ws + OFF_BNS);
    float*          BnB = (float*)(ws + OFF_BNB);
    __hip_bfloat16* W1t = (__hip_bfloat16*)(ws + OFF_W1T);

    int idx = blockIdx.x * blockDim.x + threadIdx.x;
    if (idx < 16384) {
        int a = idx >> 7, c = idx & 127;
        float s = 0.f;
        for (int o = 0; o < 128; ++o) s += wq[o * 128 + a] * wk[o * 128 + c];
        G[idx] = __float2bfloat16(s);
    } else if (idx < 32768) {
        int t = idx - 16384;
        int j = t >> 7, c = t & 127;
        WvT[t] = __float2bfloat16(wv[c * 128 + j]);
    } else if (idx < 34304) {
        int t = idx - 32768;
        int i = t >> 7, c = t & 127;
        float s = 0.f;
        for (int o = 0; o < 128; ++o)
            s += bq[o] * wk[o * 128 + c] + wq[o * 128 + c] * (rel_h[o * 12 + i] + rel_w[o]);
        Rt[t] = s;
    } else if (idx < 34432) {
        int c = idx - 34304;
        float inv = gamma[c] * rsqrtf(var[c] + 1e-5f);
        BnS[c] = inv;
        BnB[c] = beta[c] - mean[c] * inv;
    } else if (idx < 290432) {
        int t = idx - 34432;
        int j = t / 200, h = t - j * 200;
        W1t[t] = __float2bfloat16(fc1w[h * 1280 + j]);
    }
}

// ------------------------------------------------- fused attention stage ----
// block = 512 threads = 4 batch-slots x 128 channels. 32 batches per block.
__launch_bounds__(512, 1)
__global__ void attn_kernel(const float* __restrict__ x, const float* __restrict__ bv,
                            const char* __restrict__ ws, __hip_bfloat16* __restrict__ pooled)
{
    __shared__ __hip_bfloat16 sG[16384];     // 32 KB  [a][c]
    __shared__ __hip_bfloat16 sWvT[16384];   // 32 KB  [j][c]
    __shared__ float sX[4][128 * 16];        // 32 KB  [c][i] (16-pad); reused as pool staging
    __shared__ float sU[4][128 * 12];        // 24 KB  u then z, [c][i]
    __shared__ float sS[4][144];             //  2.3KB scores then attn
    __shared__ float sRt[1536];              //  6 KB
    __shared__ float sBnS[128], sBnB[128], sBv[128];

    const __hip_bfloat16* G   = (const __hip_bfloat16*)(ws + OFF_G);
    const __hip_bfloat16* WvT = (const __hip_bfloat16*)(ws + OFF_WVT);
    const float* Rt  = (const float*)(ws + OFF_RT);
    const float* BnS = (const float*)(ws + OFF_BNS);
    const float* BnB = (const float*)(ws + OFF_BNB);

    const int tid  = threadIdx.x;
    const int slot = tid >> 7;
    const int c    = tid & 127;

    for (int i = tid; i < 16384; i += 512) { sG[i] = G[i]; sWvT[i] = WvT[i]; }
    for (int i = tid; i < 1536; i += 512) sRt[i] = Rt[i];
    if (tid < 128) { sBnS[tid] = BnS[tid]; sBnB[tid] = BnB[tid]; sBv[tid] = bv[tid]; }
    __syncthreads();

    const int b0 = blockIdx.x * 32;
    for (int it = 0; it < 32; it += 4) {
        const int b = b0 + it + slot;

        // ---- load X[c][0..11] (f32, 3x float4), keep a register copy
        const float4* xp = (const float4*)(x + (size_t)b * 1536 + c * 12);
        float4 xa = xp[0], xb = xp[1], xc = xp[2];
        float xr[12] = {xa.x, xa.y, xa.z, xa.w, xb.x, xb.y, xb.z, xb.w, xc.x, xc.y, xc.z, xc.w};
        {
            float4* xdst = (float4*)&sX[slot][c * 16];
            xdst[0] = xa; xdst[1] = xb; xdst[2] = xc;
        }
        __syncthreads();

        // ---- t-GEMM: u[c][i] = R[i][c] + sum_a G[a][c] * X[a][i]
        float acc[12];
        #pragma unroll
        for (int i = 0; i < 12; ++i) acc[i] = sRt[i * 128 + c];
        #pragma unroll 4
        for (int a = 0; a < 128; ++a) {
            float g = bf2f(sG[a * 128 + c]);
            const float4* xrow = (const float4*)&sX[slot][a * 16];
            float4 r0 = xrow[0], r1 = xrow[1], r2 = xrow[2];
            acc[0] += g * r0.x; acc[1] += g * r0.y; acc[2]  += g * r0.z; acc[3]  += g * r0.w;
            acc[4] += g * r1.x; acc[5] += g * r1.y; acc[6]  += g * r1.z; acc[7]  += g * r1.w;
            acc[8] += g * r2.x; acc[9] += g * r2.y; acc[10] += g * r2.z; acc[11] += g * r2.w;
        }
        {
            float4* urow = (float4*)&sU[slot][c * 12];
            urow[0] = make_float4(acc[0], acc[1], acc[2],  acc[3]);
            urow[1] = make_float4(acc[4], acc[5], acc[6],  acc[7]);
            urow[2] = make_float4(acc[8], acc[9], acc[10], acc[11]);
        }
        __syncthreads();

        // ---- scores S[i][j] = sum_a u[a][i] * X[a][j]   (144 dots over 128)
        {
            int i1 = c / 12, j1 = c - i1 * 12;
            int p2 = c + 128;
            int i2 = p2 / 12, j2 = p2 - i2 * 12;
            bool has2 = (p2 < 144);
            float s1 = 0.f, s2 = 0.f;
            #pragma unroll 4
            for (int a = 0; a < 128; ++a) {
                s1 += sU[slot][a * 12 + i1] * sX[slot][a * 16 + j1];
                if (has2) s2 += sU[slot][a * 12 + i2] * sX[slot][a * 16 + j2];
            }
            sS[slot][c] = s1;
            if (has2) sS[slot][p2] = s2;
        }
        __syncthreads();

        // ---- softmax over j (rows i = 0..11)
        if (c < 12) {
            float* row = &sS[slot][c * 12];
            float m = row[0];
            #pragma unroll
            for (int j = 1; j < 12; ++j) m = fmaxf(m, row[j]);
            float e[12]; float sum = 0.f;
            #pragma unroll
            for (int j = 0; j < 12; ++j) { e[j] = __expf(row[j] - m); sum += e[j]; }
            float r = 1.f / sum;
            #pragma unroll
            for (int j = 0; j < 12; ++j) row[j] = e[j] * r;
        }
        __syncthreads();

        // ---- z[c][m] = sum_n X[c][n] * A[m][n]  (X from registers)
        float z[12];
        #pragma unroll
        for (int m = 0; m < 12; ++m) {
            const float4* ar = (const float4*)&sS[slot][m * 12];
            float4 a0 = ar[0], a1 = ar[1], a2 = ar[2];
            z[m] = xr[0] * a0.x + xr[1] * a0.y + xr[2]  * a0.z + xr[3]  * a0.w
                 + xr[4] * a1.x + xr[5] * a1.y + xr[6]  * a1.z + xr[7]  * a1.w
                 + xr[8] * a2.x + xr[9] * a2.y + xr[10] * a2.z + xr[11] * a2.w;
        }
        {
            float4* zrow = (float4*)&sU[slot][c * 12];
            zrow[0] = make_float4(z[0], z[1], z[2],  z[3]);
            zrow[1] = make_float4(z[4], z[5], z[6],  z[7]);
            zrow[2] = make_float4(z[8], z[9], z[10], z[11]);
        }
        __syncthreads();

        // ---- out[c][m] = bv[c] + sum_j wv[c][j] z[j][m];  BN+ReLU; pool(3)
        float oa[12];
        {
            float bvc = sBv[c];
            #pragma unroll
            for (int m = 0; m < 12; ++m) oa[m] = bvc;
        }
        #pragma unroll 4
        for (int j = 0; j < 128; ++j) {
            float w = bf2f(sWvT[j * 128 + c]);
            const float4* zr = (const float4*)&sU[slot][j * 12];
            float4 r0 = zr[0], r1 = zr[1], r2 = zr[2];
            oa[0] += w * r0.x; oa[1] += w * r0.y; oa[2]  += w * r0.z; oa[3]  += w * r0.w;
            oa[4] += w * r1.x; oa[5] += w * r1.y; oa[6]  += w * r1.z; oa[7]  += w * r1.w;
            oa[8] += w * r2.x; oa[9] += w * r2.y; oa[10] += w * r2.z; oa[11] += w * r2.w;
        }
        {
            float inv = sBnS[c], bb = sBnB[c];
            #pragma unroll
            for (int m = 0; m < 12; ++m) oa[m] = fmaxf(oa[m] * inv + bb, 0.f);
        }
        float* sp = &sX[slot][0];   // reuse as pool staging (1280 f32)
        #pragma unroll
        for (int m = 0; m < 10; ++m)
            sp[c * 10 + m] = fmaxf(fmaxf(oa[m], oa[m + 1]), oa[m + 2]);
        __syncthreads();
        {
            __hip_bfloat16* pb = pooled + (size_t)b * 1280;
            for (int i2 = c; i2 < 1280; i2 += 128) pb[i2] = __float2bfloat16(sp[i2]);
        }
        __syncthreads();
    }
}

// ----------------------------------------------------------- fc1+fc2 ----
// block = 256 threads, 16 batches; thread t<200 owns hidden unit h=t.
__launch_bounds__(256, 1)
__global__ void fc_kernel(const __hip_bfloat16* __restrict__ pooled,
                          const char* __restrict__ ws,
                          const float* __restrict__ fc1b,
                          const float* __restrict__ fc2w, const float* __restrict__ fc2b,
                          float* __restrict__ out)
{
    __shared__ float sP[16 * 1280];   // 80 KB
    __shared__ float sHid[16 * 200];  // 12.8 KB
    const __hip_bfloat16* W1t = (const __hip_bfloat16*)(ws + OFF_W1T);
    const int tid = threadIdx.x;
    const int b0  = blockIdx.x * 16;

    // load pooled (bf16) -> sP (f32), 4 elems/iter
    {
        const ushort4* src = (const ushort4*)(pooled + (size_t)b0 * 1280);
        for (int i = tid; i < 5120; i += 256) {
            ushort4 v = src[i];
            float4 f;
            f.x = __uint_as_float(((unsigned)v.x) << 16);
            f.y = __uint_as_float(((unsigned)v.y) << 16);
            f.z = __uint_as_float(((unsigned)v.z) << 16);
            f.w = __uint_as_float(((unsigned)v.w) << 16);
            ((float4*)sP)[i] = f;
        }
    }
    __syncthreads();

    if (tid < 200) {
        const int h = tid;
        float acc[16];
        #pragma unroll
        for (int b = 0; b < 16; ++b) acc[b] = 0.f;
        #pragma unroll 4
        for (int j = 0; j < 1280; j += 4) {
            float w0 = bf2f(W1t[(j + 0) * 200 + h]);
            float w1 = bf2f(W1t[(j + 1) * 200 + h]);
            float w2 = bf2f(W1t[(j + 2) * 200 + h]);
            float w3 = bf2f(W1t[(j + 3) * 200 + h]);
            #pragma unroll
            for (int b = 0; b < 16; ++b) {
                const float4 p = *(const float4*)&sP[b * 1280 + j];
                acc[b] += w0 * p.x + w1 * p.y + w2 * p.z + w3 * p.w;
            }
        }
        float bias = fc1b[h];
        #pragma unroll
        for (int b = 0; b < 16; ++b) sHid[b * 200 + h] = fmaxf(acc[b] + bias, 0.f);
    }
    __syncthreads();

    if (tid < 32) {
        int b = tid >> 1, o = tid & 1;
        float s = fc2b[o];
        const float* hp = &sHid[b * 200];
        const float* wp = fc2w + o * 200;
        #pragma unroll 8
        for (int h = 0; h < 200; ++h) s += hp[h] * wp[h];
        out[(size_t)(b0 + b) * 2 + o] = 1.f / (1.f + __expf(-s));
    }
}

// ------------------------------------------------------------- launch ----
extern "C" void kernel_launch(void* const* d_in, const int* in_sizes, int n_in,
                              void* d_out, int out_size, void* d_ws, size_t ws_size,
                              hipStream_t stream)
{
    const float* x     = (const float*)d_in[0];
    const float* wq    = (const float*)d_in[1];
    const float* bq    = (const float*)d_in[2];
    const float* wk    = (const float*)d_in[3];
    // d_in[4] = bk: cancels under softmax row-invariance — unused.
    const float* wv    = (const float*)d_in[5];
    const float* bv    = (const float*)d_in[6];
    const float* rel_h = (const float*)d_in[7];
    const float* rel_w = (const float*)d_in[8];
    const float* gamma = (const float*)d_in[9];
    const float* beta  = (const float*)d_in[10];
    const float* mean  = (const float*)d_in[11];
    const float* var   = (const float*)d_in[12];
    const float* fc1w  = (const float*)d_in[13];
    const float* fc1b  = (const float*)d_in[14];
    const float* fc2w  = (const float*)d_in[15];
    const float* fc2b  = (const float*)d_in[16];

    char* ws = (char*)d_ws;
    __hip_bfloat16* pooled = (__hip_bfloat16*)(ws + OFF_P);
    float* out = (float*)d_out;

    setup_kernel<<<1135, 256, 0, stream>>>(wq, bq, wk, rel_h, rel_w, wv,
                                           gamma, beta, mean, var, fc1w, ws);
    attn_kernel<<<1024, 512, 0, stream>>>(x, bv, ws, pooled);
    fc_kernel<<<2048, 256, 0, stream>>>(pooled, ws, fc1b, fc2w, fc2b, out);
}

// Round 2
// 658.517 us; speedup vs baseline: 2.5991x; 2.5991x over previous
//
#include <hip/hip_runtime.h>
#include <hip/hip_bf16.h>

// Workspace byte offsets
#define OFF_G    0u        // bf16 [128][128]  G[a][c] = sum_o wq[o,a]*wk[o,c]
#define OFF_WVT  32768u    // bf16 [128][128]  WvT[j][c] = wv[c][j]
#define OFF_RT   65536u    // f32  [12][128]   R[i][c]
#define OFF_BNS  71680u    // f32  [128]
#define OFF_BNB  72192u    // f32  [128]
#define OFF_FLAG 72704u    // int: 1 if MFMA fragment-layout probe verified
#define OFF_W1   72768u    // bf16 [208][1280] fc1_w rows (200 real + 8 zero pad)
#define OFF_P    605248u   // bf16 [32768][1280] pooled activations

typedef __attribute__((ext_vector_type(8))) unsigned short ushort8_t;
typedef __attribute__((ext_vector_type(8))) __bf16 bf16x8;
typedef __attribute__((ext_vector_type(4))) float f32x4;

static __device__ __forceinline__ float bfbits2f(unsigned short u) {
    return __uint_as_float(((unsigned)u) << 16);
}
static __device__ __forceinline__ unsigned short f2bfbits(float f) {
    __hip_bfloat16 h = __float2bfloat16(f);
    return *(unsigned short*)&h;
}
static __device__ __forceinline__ f32x4 mfma16x16x32(ushort8_t a, ushort8_t b, f32x4 c) {
    return __builtin_amdgcn_mfma_f32_16x16x32_bf16(
        __builtin_bit_cast(bf16x8, a), __builtin_bit_cast(bf16x8, b), c, 0, 0, 0);
}

// ---------------------------------------------------------------- setup ----
__global__ void setup_kernel(const float* __restrict__ wq, const float* __restrict__ bq,
                             const float* __restrict__ wk,
                             const float* __restrict__ rel_h, const float* __restrict__ rel_w,
                             const float* __restrict__ wv,
                             const float* __restrict__ gamma, const float* __restrict__ beta,
                             const float* __restrict__ mean, const float* __restrict__ var,
                             const float* __restrict__ fc1w,
                             char* __restrict__ ws)
{
    __hip_bfloat16* G   = (__hip_bfloat16*)(ws + OFF_G);
    __hip_bfloat16* WvT = (__hip_bfloat16*)(ws + OFF_WVT);
    float*          Rt  = (float*)(ws + OFF_RT);
    float*          BnS = (float*)(ws + OFF_BNS);
    float*          BnB = (float*)(ws + OFF_BNB);
    __hip_bfloat16* W1  = (__hip_bfloat16*)(ws + OFF_W1);

    int idx = blockIdx.x * blockDim.x + threadIdx.x;
    if (idx < 16384) {
        int a = idx >> 7, c = idx & 127;
        float s = 0.f;
        for (int o = 0; o < 128; ++o) s += wq[o * 128 + a] * wk[o * 128 + c];
        G[idx] = __float2bfloat16(s);
    } else if (idx < 32768) {
        int t = idx - 16384;
        int j = t >> 7, c = t & 127;
        WvT[t] = __float2bfloat16(wv[c * 128 + j]);
    } else if (idx < 34304) {
        int t = idx - 32768;
        int i = t >> 7, c = t & 127;
        float s = 0.f;
        for (int o = 0; o < 128; ++o)
            s += bq[o] * wk[o * 128 + c] + wq[o * 128 + c] * (rel_h[o * 12 + i] + rel_w[o]);
        Rt[t] = s;
    } else if (idx < 34432) {
        int c = idx - 34304;
        float inv = gamma[c] * rsqrtf(var[c] + 1e-5f);
        BnS[c] = inv;
        BnB[c] = beta[c] - mean[c] * inv;
    } else if (idx < 300672) {
        int t = idx - 34432;            // [208][1280]: h = t/1280, k = t%1280
        int h = t / 1280, k = t - h * 1280;
        W1[t] = (h < 200) ? __float2bfloat16(fc1w[h * 1280 + k]) : __float2bfloat16(0.f);
    } else if (idx < 300736) {
        // ---- MFMA fragment-layout probe (one full wave) ----
        // Assumed layouts: A[m= l&15][k=(l>>4)*8+j]; B[k=(l>>4)*8+j][n= l&15];
        // D[row=(l>>4)*4+r][col= l&15] (D verified: learn_hip m89).
        int l = idx - 300672;
        int m = l & 15, g = l >> 4;
        ushort8_t av, bv8;
        for (int j = 0; j < 8; ++j) {
            int k = g * 8 + j;
            float aval = (float)(((m * 5 + k * 3) % 7) - 3);   // exact small ints
            float bval = (float)(((k * 11 + m * 2) % 5) - 2);
            av[j]  = (unsigned short)(__float_as_uint(aval) >> 16);
            bv8[j] = (unsigned short)(__float_as_uint(bval) >> 16);
        }
        f32x4 zero = {0.f, 0.f, 0.f, 0.f};
        f32x4 d = mfma16x16x32(av, bv8, zero);
        bool ok = true;
        int col = l & 15;
        for (int r = 0; r < 4; ++r) {
            int row = g * 4 + r;
            float ref = 0.f;
            for (int k = 0; k < 32; ++k)
                ref += (float)(((row * 5 + k * 3) % 7) - 3) *
                       (float)(((k * 11 + col * 2) % 5) - 2);
            if (d[r] != ref) ok = false;
        }
        unsigned long long ball = __ballot(ok ? 1 : 0);
        if (l == 0) *(int*)(ws + OFF_FLAG) = (ball == ~0ull) ? 1 : 0;
    }
}

// ------------------------------------------------- fused attention stage ----
// 256 threads = 2 batch-slots x 128 channels; 16 batches/block; G/WvT from
// global (L1/L2-resident) so LDS ~37KB -> 4 blocks/CU (16 waves/CU).
__launch_bounds__(256, 4)
__global__ void attn_kernel(const float* __restrict__ x, const float* __restrict__ bv,
                            const char* __restrict__ ws, __hip_bfloat16* __restrict__ pooled)
{
    __shared__ float sX[2][128 * 16];        // 16 KB  [c][i]; reused as pool staging
    __shared__ float sU[2][128 * 12];        // 12 KB  u then z, [c][i]
    __shared__ float sS[2][144];             //  1.2KB scores then attn
    __shared__ float sRt[1536];              //  6 KB
    __shared__ float sBnS[128], sBnB[128], sBv[128];

    const unsigned short* Gu  = (const unsigned short*)(ws + OFF_G);
    const unsigned short* Wvu = (const unsigned short*)(ws + OFF_WVT);
    const float* Rt  = (const float*)(ws + OFF_RT);
    const float* BnS = (const float*)(ws + OFF_BNS);
    const float* BnB = (const float*)(ws + OFF_BNB);

    const int tid  = threadIdx.x;
    const int slot = tid >> 7;
    const int c    = tid & 127;

    for (int i = tid; i < 1536; i += 256) sRt[i] = Rt[i];
    if (tid < 128) { sBnS[tid] = BnS[tid]; sBnB[tid] = BnB[tid]; sBv[tid] = bv[tid]; }
    __syncthreads();

    const int b0 = blockIdx.x * 16;
    for (int it = 0; it < 16; it += 2) {
        const int b = b0 + it + slot;

        // ---- load X[c][0..11] (f32, 3x float4), keep a register copy
        const float4* xp = (const float4*)(x + (size_t)b * 1536 + c * 12);
        float4 xa = xp[0], xb = xp[1], xc = xp[2];
        float xr[12] = {xa.x, xa.y, xa.z, xa.w, xb.x, xb.y, xb.z, xb.w, xc.x, xc.y, xc.z, xc.w};
        {
            float4* xdst = (float4*)&sX[slot][c * 16];
            xdst[0] = xa; xdst[1] = xb; xdst[2] = xc;
        }
        __syncthreads();

        // ---- t-GEMM: u[c][i] = R[i][c] + sum_a G[a][c] * X[a][i]
        float acc[12];
        #pragma unroll
        for (int i = 0; i < 12; ++i) acc[i] = sRt[i * 128 + c];
        #pragma unroll 4
        for (int a = 0; a < 128; ++a) {
            float g = bfbits2f(Gu[a * 128 + c]);
            const float4* xrow = (const float4*)&sX[slot][a * 16];
            float4 r0 = xrow[0], r1 = xrow[1], r2 = xrow[2];
            acc[0] += g * r0.x; acc[1] += g * r0.y; acc[2]  += g * r0.z; acc[3]  += g * r0.w;
            acc[4] += g * r1.x; acc[5] += g * r1.y; acc[6]  += g * r1.z; acc[7]  += g * r1.w;
            acc[8] += g * r2.x; acc[9] += g * r2.y; acc[10] += g * r2.z; acc[11] += g * r2.w;
        }
        {
            float4* urow = (float4*)&sU[slot][c * 12];
            urow[0] = make_float4(acc[0], acc[1], acc[2],  acc[3]);
            urow[1] = make_float4(acc[4], acc[5], acc[6],  acc[7]);
            urow[2] = make_float4(acc[8], acc[9], acc[10], acc[11]);
        }
        __syncthreads();

        // ---- scores S[i][j] = sum_a u[a][i] * X[a][j]
        {
            int i1 = c / 12, j1 = c - i1 * 12;
            int p2 = c + 128;
            int i2 = p2 / 12, j2 = p2 - i2 * 12;
            bool has2 = (p2 < 144);
            float s1 = 0.f, s2 = 0.f;
            #pragma unroll 4
            for (int a = 0; a < 128; ++a) {
                s1 += sU[slot][a * 12 + i1] * sX[slot][a * 16 + j1];
                if (has2) s2 += sU[slot][a * 12 + i2] * sX[slot][a * 16 + j2];
            }
            sS[slot][c] = s1;
            if (has2) sS[slot][p2] = s2;
        }
        __syncthreads();

        // ---- softmax over j
        if (c < 12) {
            float* row = &sS[slot][c * 12];
            float m = row[0];
            #pragma unroll
            for (int j = 1; j < 12; ++j) m = fmaxf(m, row[j]);
            float e[12]; float sum = 0.f;
            #pragma unroll
            for (int j = 0; j < 12; ++j) { e[j] = __expf(row[j] - m); sum += e[j]; }
            float r = 1.f / sum;
            #pragma unroll
            for (int j = 0; j < 12; ++j) row[j] = e[j] * r;
        }
        __syncthreads();

        // ---- z[c][m] = sum_n X[c][n] * A[m][n]
        float z[12];
        #pragma unroll
        for (int m = 0; m < 12; ++m) {
            const float4* ar = (const float4*)&sS[slot][m * 12];
            float4 a0 = ar[0], a1 = ar[1], a2 = ar[2];
            z[m] = xr[0] * a0.x + xr[1] * a0.y + xr[2]  * a0.z + xr[3]  * a0.w
                 + xr[4] * a1.x + xr[5] * a1.y + xr[6]  * a1.z + xr[7]  * a1.w
                 + xr[8] * a2.x + xr[9] * a2.y + xr[10] * a2.z + xr[11] * a2.w;
        }
        {
            float4* zrow = (float4*)&sU[slot][c * 12];
            zrow[0] = make_float4(z[0], z[1], z[2],  z[3]);
            zrow[1] = make_float4(z[4], z[5], z[6],  z[7]);
            zrow[2] = make_float4(z[8], z[9], z[10], z[11]);
        }
        __syncthreads();

        // ---- out[c][m] = bv[c] + sum_j wv[c][j] z[j][m];  BN+ReLU; pool(3)
        float oa[12];
        {
            float bvc = sBv[c];
            #pragma unroll
            for (int m = 0; m < 12; ++m) oa[m] = bvc;
        }
        #pragma unroll 4
        for (int j = 0; j < 128; ++j) {
            float w = bfbits2f(Wvu[j * 128 + c]);
            const float4* zr = (const float4*)&sU[slot][j * 12];
            float4 r0 = zr[0], r1 = zr[1], r2 = zr[2];
            oa[0] += w * r0.x; oa[1] += w * r0.y; oa[2]  += w * r0.z; oa[3]  += w * r0.w;
            oa[4] += w * r1.x; oa[5] += w * r1.y; oa[6]  += w * r1.z; oa[7]  += w * r1.w;
            oa[8] += w * r2.x; oa[9] += w * r2.y; oa[10] += w * r2.z; oa[11] += w * r2.w;
        }
        {
            float inv = sBnS[c], bb = sBnB[c];
            #pragma unroll
            for (int m = 0; m < 12; ++m) oa[m] = fmaxf(oa[m] * inv + bb, 0.f);
        }
        float* sp = &sX[slot][0];   // reuse as pool staging (1280 f32)
        #pragma unroll
        for (int m = 0; m < 10; ++m)
            sp[c * 10 + m] = fmaxf(fmaxf(oa[m], oa[m + 1]), oa[m + 2]);
        __syncthreads();
        {
            __hip_bfloat16* pb = pooled + (size_t)b * 1280;
            for (int i2 = c; i2 < 1280; i2 += 128) pb[i2] = __float2bfloat16(sp[i2]);
        }
        __syncthreads();
    }
}

// ----------------------------------------------------------- fc1+fc2 ----
// MFMA GEMM: M=32768 (batch), N=200(->208), K=1280. Block: BM=128, 8 waves,
// BK=32, double-buffered LDS; fused bias+ReLU, fc2+sigmoid. VALU fallback if
// the setup probe rejected the assumed fragment layout.
__launch_bounds__(512, 1)
__global__ void fc_kernel(const __hip_bfloat16* __restrict__ pooled_bf,
                          const char* __restrict__ ws,
                          const float* __restrict__ fc1b,
                          const float* __restrict__ fc2w, const float* __restrict__ fc2b,
                          float* __restrict__ out)
{
    __shared__ char smem[54272];
    // staging: Pt0 @0 (8KB), W1t0 @8192 (13312B), Pt1 @21504, W1t1 @29696 (end 43008)
    // phase2:  hid bf16 [128][210] @0 (53760B)
    const int tid = threadIdx.x;
    const int b0  = blockIdx.x * 128;
    const unsigned short* P  = (const unsigned short*)pooled_bf;
    const unsigned short* W1 = (const unsigned short*)(ws + OFF_W1);
    unsigned short* hid = (unsigned short*)smem;
    const int flag = *(const int*)(ws + OFF_FLAG);

    if (flag) {
        const int l = tid & 63, w = tid >> 6;     // lane, wave(=M-tile)
        const int lrow = l & 15, g = l >> 4;
        f32x4 acc[13];
        #pragma unroll
        for (int nt = 0; nt < 13; ++nt) acc[nt] = (f32x4){0.f, 0.f, 0.f, 0.f};

        const int pr = tid >> 2, pc = tid & 3;     // P tile: row, 16B chunk
        const size_t pbase = (size_t)(b0 + pr) * 1280 + pc * 8;
        const int i1 = tid, i2 = tid + 512;        // W1 tile: 832 chunks of 16B
        const int h1 = i1 >> 2, c1 = i1 & 3;
        const int h2 = i2 >> 2, c2 = i2 & 3;
        const bool has2 = (i2 < 832);

        ushort8_t pReg, w1a, w1b;
        pReg = *(const ushort8_t*)(P + pbase);
        w1a  = *(const ushort8_t*)(W1 + (size_t)h1 * 1280 + c1 * 8);
        if (has2) w1b = *(const ushort8_t*)(W1 + (size_t)h2 * 1280 + c2 * 8);
        *(ushort8_t*)(smem + tid * 16) = pReg;
        *(ushort8_t*)(smem + 8192 + i1 * 16) = w1a;
        if (has2) *(ushort8_t*)(smem + 8192 + i2 * 16) = w1b;
        __syncthreads();

        int cur = 0;
        for (int ks = 0; ks < 40; ++ks) {
            if (ks + 1 < 40) {
                pReg = *(const ushort8_t*)(P + pbase + (size_t)(ks + 1) * 32);
                w1a  = *(const ushort8_t*)(W1 + (size_t)h1 * 1280 + (ks + 1) * 32 + c1 * 8);
                if (has2) w1b = *(const ushort8_t*)(W1 + (size_t)h2 * 1280 + (ks + 1) * 32 + c2 * 8);
            }
            const unsigned short* Pt = (const unsigned short*)(smem + (cur ? 21504 : 0));
            const unsigned short* Wt = (const unsigned short*)(smem + (cur ? 29696 : 8192));
            ushort8_t A = *(const ushort8_t*)(Pt + (w * 16 + lrow) * 32 + g * 8);
            #pragma unroll
            for (int nt = 0; nt < 13; ++nt) {
                ushort8_t Bf = *(const ushort8_t*)(Wt + (nt * 16 + lrow) * 32 + g * 8);
                acc[nt] = mfma16x16x32(A, Bf, acc[nt]);
            }
            __syncthreads();
            if (ks + 1 < 40) {
                char* dp = smem + ((cur ^ 1) ? 21504 : 0);
                char* dw = smem + ((cur ^ 1) ? 29696 : 8192);
                *(ushort8_t*)(dp + tid * 16) = pReg;
                *(ushort8_t*)(dw + i1 * 16) = w1a;
                if (has2) *(ushort8_t*)(dw + i2 * 16) = w1b;
            }
            __syncthreads();
            cur ^= 1;
        }
        // epilogue: bias + ReLU -> hid[row][h] bf16
        #pragma unroll
        for (int nt = 0; nt < 13; ++nt) {
            int h = nt * 16 + lrow;
            float bias = (h < 200) ? fc1b[h] : 0.f;
            #pragma unroll
            for (int r = 0; r < 4; ++r) {
                float v = fmaxf(acc[nt][r] + bias, 0.f);
                int row = w * 16 + g * 4 + r;
                hid[row * 210 + h] = f2bfbits(v);
            }
        }
    } else {
        // ---- VALU fallback (layout probe failed) ----
        for (int i = tid; i < 128 * 200; i += 512) {
            int bb = i / 200, h = i - bb * 200;
            float s = fc1b[h];
            const unsigned short* prow = P + (size_t)(b0 + bb) * 1280;
            const unsigned short* wrow = W1 + (size_t)h * 1280;
            for (int j = 0; j < 1280; ++j)
                s += bfbits2f(prow[j]) * bfbits2f(wrow[j]);
            hid[bb * 210 + h] = f2bfbits(fmaxf(s, 0.f));
        }
    }
    __syncthreads();

    // ---- fc2 + sigmoid: 256 outputs (128 b x 2 o)
    if (tid < 256) {
        int bb = tid >> 1, o = tid & 1;
        float s = fc2b[o];
        const unsigned short* hp = hid + bb * 210;
        const float* wp = fc2w + o * 200;
        #pragma unroll 8
        for (int j = 0; j < 200; ++j)
            s += bfbits2f(hp[j]) * wp[j];
        out[(size_t)(b0 + bb) * 2 + o] = 1.f / (1.f + __expf(-s));
    }
}

// ------------------------------------------------------------- launch ----
extern "C" void kernel_launch(void* const* d_in, const int* in_sizes, int n_in,
                              void* d_out, int out_size, void* d_ws, size_t ws_size,
                              hipStream_t stream)
{
    const float* x     = (const float*)d_in[0];
    const float* wq    = (const float*)d_in[1];
    const float* bq    = (const float*)d_in[2];
    const float* wk    = (const float*)d_in[3];
    // d_in[4] = bk: cancels under softmax row-invariance — unused.
    const float* wv    = (const float*)d_in[5];
    const float* bv    = (const float*)d_in[6];
    const float* rel_h = (const float*)d_in[7];
    const float* rel_w = (const float*)d_in[8];
    const float* gamma = (const float*)d_in[9];
    const float* beta  = (const float*)d_in[10];
    const float* mean  = (const float*)d_in[11];
    const float* var   = (const float*)d_in[12];
    const float* fc1w  = (const float*)d_in[13];
    const float* fc1b  = (const float*)d_in[14];
    const float* fc2w  = (const float*)d_in[15];
    const float* fc2b  = (const float*)d_in[16];

    char* ws = (char*)d_ws;
    __hip_bfloat16* pooled = (__hip_bfloat16*)(ws + OFF_P);
    float* out = (float*)d_out;

    setup_kernel<<<1175, 256, 0, stream>>>(wq, bq, wk, rel_h, rel_w, wv,
                                           gamma, beta, mean, var, fc1w, ws);
    attn_kernel<<<2048, 256, 0, stream>>>(x, bv, ws, pooled);
    fc_kernel<<<256, 512, 0, stream>>>(pooled, ws, fc1b, fc2w, fc2b, out);
}

// Round 4
// 291.973 us; speedup vs baseline: 5.8620x; 2.2554x over previous
//
#include <hip/hip_runtime.h>
#include <hip/hip_bf16.h>

// Workspace byte offsets
#define OFF_G    0u        // bf16 [128][128]  GA[oc][ic] = sum_o wq[o,ic]*wk[o,oc]
#define OFF_WVT  32768u    // bf16 [128][128]  WA[c][j] = wv[c][j]
#define OFF_RT   65536u    // f32  [128][12]   Rm[c][i]
#define OFF_BNS  71680u    // f32  [128]
#define OFF_BNB  72192u    // f32  [128]
#define OFF_FLAG 72704u    // int: 1 if MFMA fragment-layout probe verified
#define OFF_W1   72768u    // bf16 [208][1280] fc1 weights, k = m*128+c order
#define OFF_P    605248u   // bf16 [32768][1280] pooled, k = m*128+c order

typedef __attribute__((ext_vector_type(8))) unsigned short ushort8_t;
typedef __attribute__((ext_vector_type(8))) __bf16 bf16x8;
typedef __attribute__((ext_vector_type(4))) float f32x4;

static __device__ __forceinline__ float bfbits2f(unsigned short u) {
    return __uint_as_float(((unsigned)u) << 16);
}
static __device__ __forceinline__ unsigned short f2bfbits(float f) {
    __hip_bfloat16 h = __float2bfloat16(f);
    return *(unsigned short*)&h;
}
static __device__ __forceinline__ unsigned pack2bf(float a, float b) {
    return (unsigned)f2bfbits(a) | ((unsigned)f2bfbits(b) << 16);
}
static __device__ __forceinline__ f32x4 mfma16x16x32(ushort8_t a, ushort8_t b, f32x4 c) {
    return __builtin_amdgcn_mfma_f32_16x16x32_bf16(
        __builtin_bit_cast(bf16x8, a), __builtin_bit_cast(bf16x8, b), c, 0, 0, 0);
}

// ---------------------------------------------------------------- setup ----
__global__ void setup_kernel(const float* __restrict__ wq, const float* __restrict__ bq,
                             const float* __restrict__ wk,
                             const float* __restrict__ rel_h, const float* __restrict__ rel_w,
                             const float* __restrict__ wv,
                             const float* __restrict__ gamma, const float* __restrict__ beta,
                             const float* __restrict__ mean, const float* __restrict__ var,
                             const float* __restrict__ fc1w,
                             char* __restrict__ ws)
{
    __hip_bfloat16* GA  = (__hip_bfloat16*)(ws + OFF_G);
    __hip_bfloat16* WA  = (__hip_bfloat16*)(ws + OFF_WVT);
    float*          Rm  = (float*)(ws + OFF_RT);
    float*          BnS = (float*)(ws + OFF_BNS);
    float*          BnB = (float*)(ws + OFF_BNB);
    __hip_bfloat16* W1  = (__hip_bfloat16*)(ws + OFF_W1);

    int idx = blockIdx.x * blockDim.x + threadIdx.x;
    if (idx < 16384) {
        int c = idx >> 7, a = idx & 127;     // GA[c][a] = sum_o wq[o,a]*wk[o,c]
        float s = 0.f;
        for (int o = 0; o < 128; ++o) s += wq[o * 128 + a] * wk[o * 128 + c];
        GA[idx] = __float2bfloat16(s);
    } else if (idx < 32768) {
        int t = idx - 16384;                 // WA = wv direct (row-major [c][j])
        WA[t] = __float2bfloat16(wv[t]);
    } else if (idx < 34304) {
        int t = idx - 32768;                 // Rm[c][i]
        int c = t / 12, i = t - c * 12;
        float s = 0.f;
        for (int o = 0; o < 128; ++o)
            s += bq[o] * wk[o * 128 + c] + wq[o * 128 + c] * (rel_h[o * 12 + i] + rel_w[o]);
        Rm[t] = s;
    } else if (idx < 34432) {
        int c = idx - 34304;
        float inv = gamma[c] * rsqrtf(var[c] + 1e-5f);
        BnS[c] = inv;
        BnB[c] = beta[c] - mean[c] * inv;
    } else if (idx < 300672) {
        int t = idx - 34432;                 // W1[h][m*128+c] = fc1w[h][c*10+m]
        int h = t / 1280, k = t - h * 1280;
        int m = k >> 7, c = k & 127;
        W1[t] = (h < 200) ? __float2bfloat16(fc1w[h * 1280 + c * 10 + m])
                          : __float2bfloat16(0.f);
    } else if (idx < 300736) {
        // ---- MFMA fragment-layout probe (one full wave) ----
        int l = idx - 300672;
        int m = l & 15, g = l >> 4;
        ushort8_t av, bv8;
        for (int j = 0; j < 8; ++j) {
            int k = g * 8 + j;
            float aval = (float)(((m * 5 + k * 3) % 7) - 3);
            float bval = (float)(((k * 11 + m * 2) % 5) - 2);
            av[j]  = (unsigned short)(__float_as_uint(aval) >> 16);
            bv8[j] = (unsigned short)(__float_as_uint(bval) >> 16);
        }
        f32x4 zero = {0.f, 0.f, 0.f, 0.f};
        f32x4 d = mfma16x16x32(av, bv8, zero);
        bool ok = true;
        int col = l & 15;
        for (int r = 0; r < 4; ++r) {
            int row = g * 4 + r;
            float ref = 0.f;
            for (int k = 0; k < 32; ++k)
                ref += (float)(((row * 5 + k * 3) % 7) - 3) *
                       (float)(((k * 11 + col * 2) % 5) - 2);
            if (d[r] != ref) ok = false;
        }
        unsigned long long ball = __ballot(ok ? 1 : 0);
        if (l == 0) *(int*)(ws + OFF_FLAG) = (ball == ~0ull) ? 1 : 0;
    }
}

// ------------------------------------------------- MFMA attention stage ----
// 256 thr = 4 waves. 4 batches/group, 4 groups/block. Wave w owns output-
// channel M-tiles {w, w+4}; G/Wv A-fragments resident in VGPRs.
// LDS layout (bytes): XB [0,14336) | TZ [14336,28672) | XO [28672,45056) |
//                     PP [45056,47104) | Rm [47104,53248)  — exact fit.
#define XB_H   0        // Xb  [56][128] u16, chunk-XOR swizzled; overlaid by OutL[128][50]
#define TZ_H   7168     // T/Z [56][128] u16, same swizzle (half-index offsets)
#define XO_H   14336    // X_orig [4][128][16] u16 (pos cols 12-15 zero)
#define PP_H   22528    // P [4][16][16] u16
#define RM_F   11776    // Rm [128][12] f32 (byte offset 47104; ends 53248)

__launch_bounds__(256, 3)
__global__ void attn_kernel(const float* __restrict__ x, const float* __restrict__ bv,
                            const char* __restrict__ ws, __hip_bfloat16* __restrict__ pooled)
{
    __shared__ __align__(16) char lds[53248];
    unsigned short* LH = (unsigned short*)lds;
    float* RmL = (float*)lds + RM_F;

    const int tid = threadIdx.x;
    const int w = tid >> 6, l = tid & 63, g = l >> 4, lr = l & 15;

    const unsigned short* GA  = (const unsigned short*)(ws + OFF_G);
    const unsigned short* WA  = (const unsigned short*)(ws + OFF_WVT);
    const float* Rm  = (const float*)(ws + OFF_RT);
    const float* BnS = (const float*)(ws + OFF_BNS);
    const float* BnB = (const float*)(ws + OFF_BNB);

    // persistent per-wave weight fragments + per-lane BN/bias constants
    ushort8_t gfrag[2][4], wfrag[2][4];
    float bns[2][4], bnb[2][4], bvv[2][4];
    #pragma unroll
    for (int mi = 0; mi < 2; ++mi) {
        int mt = w + mi * 4;
        #pragma unroll
        for (int kt = 0; kt < 4; ++kt) {
            gfrag[mi][kt] = *(const ushort8_t*)(GA + (mt * 16 + lr) * 128 + kt * 32 + g * 8);
            wfrag[mi][kt] = *(const ushort8_t*)(WA + (mt * 16 + lr) * 128 + kt * 32 + g * 8);
        }
        #pragma unroll
        for (int r = 0; r < 4; ++r) {
            int oc = mt * 16 + g * 4 + r;
            bns[mi][r] = BnS[oc]; bnb[mi][r] = BnB[oc]; bvv[mi][r] = bv[oc];
        }
    }
    for (int i = tid; i < 1536; i += 256) RmL[i] = Rm[i];

    const ushort8_t zero8 = {0, 0, 0, 0, 0, 0, 0, 0};

    for (int grp = 0; grp < 4; ++grp) {
        const int b0g = blockIdx.x * 16 + grp * 4;
        __syncthreads();   // protect prior group's OutL reads / RmL first use

        // ---- load X into Xb (swizzled [n][c]) and X_orig ([c][pos], zero-pad)
        {
            const int c = tid & 127, bh = tid >> 7;
            #pragma unroll
            for (int bb = 0; bb < 2; ++bb) {
                int bl = bh * 2 + bb;
                const float4* xp = (const float4*)(x + ((size_t)(b0g + bl) * 128 + c) * 12);
                float4 xa = xp[0], xb4 = xp[1], xc4 = xp[2];
                float xv[12] = {xa.x, xa.y, xa.z, xa.w, xb4.x, xb4.y, xb4.z, xb4.w,
                                xc4.x, xc4.y, xc4.z, xc4.w};
                unsigned short h[12];
                #pragma unroll
                for (int i = 0; i < 12; ++i) h[i] = f2bfbits(xv[i]);
                ushort8_t lo = {h[0], h[1], h[2], h[3], h[4], h[5], h[6], h[7]};
                ushort8_t hi = {h[8], h[9], h[10], h[11], 0, 0, 0, 0};
                *(ushort8_t*)(LH + XO_H + (bl * 128 + c) * 16)     = lo;
                *(ushort8_t*)(LH + XO_H + (bl * 128 + c) * 16 + 8) = hi;
                #pragma unroll
                for (int i = 0; i < 12; ++i) {
                    int n = bl * 12 + i;
                    LH[XB_H + n * 128 + (((c >> 3) ^ (n & 15)) << 3) + (c & 7)] = h[i];
                }
            }
        }
        __syncthreads();

        // ---- stage 1: t' = G^T X (+R), transpose-write to TZ
        #pragma unroll
        for (int nt = 0; nt < 3; ++nt) {
            int n = nt * 16 + lr, sw = n & 15;
            ushort8_t bf[4];
            #pragma unroll
            for (int kt = 0; kt < 4; ++kt)
                bf[kt] = *(const ushort8_t*)(LH + XB_H + n * 128 + ((((kt << 2) + g) ^ sw) << 3));
            int bb = n / 12, ii = n - bb * 12;
            #pragma unroll
            for (int mi = 0; mi < 2; ++mi) {
                int mt = w + mi * 4;
                f32x4 acc = {0.f, 0.f, 0.f, 0.f};
                #pragma unroll
                for (int kt = 0; kt < 4; ++kt) acc = mfma16x16x32(gfrag[mi][kt], bf[kt], acc);
                int ocb = mt * 16 + g * 4;
                float v0 = acc[0] + RmL[(ocb + 0) * 12 + ii];
                float v1 = acc[1] + RmL[(ocb + 1) * 12 + ii];
                float v2 = acc[2] + RmL[(ocb + 2) * 12 + ii];
                float v3 = acc[3] + RmL[(ocb + 3) * 12 + ii];
                int cc = ocb >> 3;
                unsigned off = TZ_H + n * 128 + (((cc ^ sw) << 3) + ((g & 1) << 2));
                *(unsigned*)(LH + off)     = pack2bf(v0, v1);
                *(unsigned*)(LH + off + 2) = pack2bf(v2, v3);
            }
        }
        __syncthreads();

        // ---- stage 2: S = u^T X for batch w; softmax; write P
        {
            int n = w * 12 + lr, sw = n & 15;
            f32x4 s = {0.f, 0.f, 0.f, 0.f};
            #pragma unroll
            for (int kt = 0; kt < 4; ++kt) {
                unsigned ch = (((kt << 2) + g) ^ sw) << 3;
                ushort8_t af = *(const ushort8_t*)(LH + TZ_H + n * 128 + ch);
                ushort8_t bf = *(const ushort8_t*)(LH + XB_H + n * 128 + ch);
                s = mfma16x16x32(af, bf, s);
            }
            bool jv = (lr < 12);
            float mx[4], ev[4], sum[4];
            #pragma unroll
            for (int r = 0; r < 4; ++r) mx[r] = jv ? s[r] : -3.0e38f;
            #pragma unroll
            for (int d = 1; d < 16; d <<= 1) {
                #pragma unroll
                for (int r = 0; r < 4; ++r) mx[r] = fmaxf(mx[r], __shfl_xor(mx[r], d));
            }
            #pragma unroll
            for (int r = 0; r < 4; ++r) { ev[r] = jv ? __expf(s[r] - mx[r]) : 0.f; sum[r] = ev[r]; }
            #pragma unroll
            for (int d = 1; d < 16; d <<= 1) {
                #pragma unroll
                for (int r = 0; r < 4; ++r) sum[r] += __shfl_xor(sum[r], d);
            }
            #pragma unroll
            for (int r = 0; r < 4; ++r)
                LH[PP_H + w * 256 + (g * 4 + r) * 16 + lr] = f2bfbits(ev[r] / sum[r]);
        }
        __syncthreads();

        // ---- stage 4: Z = X . P^T  (K = pos, zero-padded via zero fragments)
        #pragma unroll
        for (int bb = 0; bb < 4; ++bb) {
            ushort8_t bfP = (g < 2) ? *(const ushort8_t*)(LH + PP_H + bb * 256 + lr * 16 + g * 8)
                                    : zero8;
            #pragma unroll
            for (int mi = 0; mi < 2; ++mi) {
                int mt = w + mi * 4;
                ushort8_t af = (g < 2)
                    ? *(const ushort8_t*)(LH + XO_H + (bb * 128 + mt * 16 + lr) * 16 + g * 8)
                    : zero8;
                f32x4 zacc = {0.f, 0.f, 0.f, 0.f};
                zacc = mfma16x16x32(af, bfP, zacc);
                if (lr < 12) {
                    int n = bb * 12 + lr, sw = n & 15;
                    int ocb = mt * 16 + g * 4, cc = ocb >> 3;
                    unsigned off = TZ_H + n * 128 + (((cc ^ sw) << 3) + ((g & 1) << 2));
                    *(unsigned*)(LH + off)     = pack2bf(zacc[0], zacc[1]);
                    *(unsigned*)(LH + off + 2) = pack2bf(zacc[2], zacc[3]);
                }
            }
        }
        __syncthreads();

        // ---- stage 5: out = Wv Z + bv; BN+ReLU; write OutL[oc][n] (stride 50)
        #pragma unroll
        for (int nt = 0; nt < 3; ++nt) {
            int n = nt * 16 + lr, sw = n & 15;
            ushort8_t bf[4];
            #pragma unroll
            for (int kt = 0; kt < 4; ++kt)
                bf[kt] = *(const ushort8_t*)(LH + TZ_H + n * 128 + ((((kt << 2) + g) ^ sw) << 3));
            #pragma unroll
            for (int mi = 0; mi < 2; ++mi) {
                int mt = w + mi * 4;
                f32x4 acc = {bvv[mi][0], bvv[mi][1], bvv[mi][2], bvv[mi][3]};
                #pragma unroll
                for (int kt = 0; kt < 4; ++kt) acc = mfma16x16x32(wfrag[mi][kt], bf[kt], acc);
                #pragma unroll
                for (int r = 0; r < 4; ++r) {
                    float val = fmaxf(acc[r] * bns[mi][r] + bnb[mi][r], 0.f);
                    int oc = mt * 16 + g * 4 + r;
                    LH[XB_H + oc * 50 + n] = f2bfbits(val);
                }
            }
        }
        __syncthreads();

        // ---- pool(3) along pos + coalesced u32 stores, layout [b][m*128+c]
        {
            int c2 = tid & 63, sub = tid >> 6;
            unsigned* pout = (unsigned*)pooled;
            const size_t obase = (size_t)(b0g + sub) * 640;
            #pragma unroll
            for (int m = 0; m < 10; ++m) {
                int base = sub * 12 + m;
                int r0 = XB_H + (c2 * 2) * 50 + base;
                int r1 = r0 + 50;
                float a0 = bfbits2f(LH[r0]),     a1 = bfbits2f(LH[r0 + 1]), a2 = bfbits2f(LH[r0 + 2]);
                float b0 = bfbits2f(LH[r1]),     b1 = bfbits2f(LH[r1 + 1]), b2 = bfbits2f(LH[r1 + 2]);
                float v0 = fmaxf(fmaxf(a0, a1), a2);
                float v1 = fmaxf(fmaxf(b0, b1), b2);
                pout[obase + m * 64 + c2] = pack2bf(v0, v1);
            }
        }
    }
}

// ----------------------------------------------------------- fc1+fc2 ----
__launch_bounds__(512, 1)
__global__ void fc_kernel(const __hip_bfloat16* __restrict__ pooled_bf,
                          const char* __restrict__ ws,
                          const float* __restrict__ fc1b,
                          const float* __restrict__ fc2w, const float* __restrict__ fc2b,
                          float* __restrict__ out)
{
    __shared__ char smem[54272];
    const int tid = threadIdx.x;
    const int b0  = blockIdx.x * 128;
    const unsigned short* P  = (const unsigned short*)pooled_bf;
    const unsigned short* W1 = (const unsigned short*)(ws + OFF_W1);
    unsigned short* hid = (unsigned short*)smem;
    const int flag = *(const int*)(ws + OFF_FLAG);

    if (flag) {
        const int l = tid & 63, w = tid >> 6;
        const int lrow = l & 15, g = l >> 4;
        f32x4 acc[13];
        #pragma unroll
        for (int nt = 0; nt < 13; ++nt) acc[nt] = (f32x4){0.f, 0.f, 0.f, 0.f};

        const int pr = tid >> 2, pc = tid & 3;
        const size_t pbase = (size_t)(b0 + pr) * 1280 + pc * 8;
        const int i1 = tid, i2 = tid + 512;
        const int h1 = i1 >> 2, c1 = i1 & 3;
        const int h2 = i2 >> 2, c2 = i2 & 3;
        const bool has2 = (i2 < 832);

        ushort8_t pReg, w1a, w1b;
        pReg = *(const ushort8_t*)(P + pbase);
        w1a  = *(const ushort8_t*)(W1 + (size_t)h1 * 1280 + c1 * 8);
        if (has2) w1b = *(const ushort8_t*)(W1 + (size_t)h2 * 1280 + c2 * 8);
        *(ushort8_t*)(smem + tid * 16) = pReg;
        *(ushort8_t*)(smem + 8192 + i1 * 16) = w1a;
        if (has2) *(ushort8_t*)(smem + 8192 + i2 * 16) = w1b;
        __syncthreads();

        int cur = 0;
        for (int ks = 0; ks < 40; ++ks) {
            if (ks + 1 < 40) {
                pReg = *(const ushort8_t*)(P + pbase + (size_t)(ks + 1) * 32);
                w1a  = *(const ushort8_t*)(W1 + (size_t)h1 * 1280 + (ks + 1) * 32 + c1 * 8);
                if (has2) w1b = *(const ushort8_t*)(W1 + (size_t)h2 * 1280 + (ks + 1) * 32 + c2 * 8);
            }
            const unsigned short* Pt = (const unsigned short*)(smem + (cur ? 21504 : 0));
            const unsigned short* Wt = (const unsigned short*)(smem + (cur ? 29696 : 8192));
            ushort8_t A = *(const ushort8_t*)(Pt + (w * 16 + lrow) * 32 + g * 8);
            #pragma unroll
            for (int nt = 0; nt < 13; ++nt) {
                ushort8_t Bf = *(const ushort8_t*)(Wt + (nt * 16 + lrow) * 32 + g * 8);
                acc[nt] = mfma16x16x32(A, Bf, acc[nt]);
            }
            __syncthreads();
            if (ks + 1 < 40) {
                char* dp = smem + ((cur ^ 1) ? 21504 : 0);
                char* dw = smem + ((cur ^ 1) ? 29696 : 8192);
                *(ushort8_t*)(dp + tid * 16) = pReg;
                *(ushort8_t*)(dw + i1 * 16) = w1a;
                if (has2) *(ushort8_t*)(dw + i2 * 16) = w1b;
            }
            __syncthreads();
            cur ^= 1;
        }
        #pragma unroll
        for (int nt = 0; nt < 13; ++nt) {
            int h = nt * 16 + lrow;
            float bias = (h < 200) ? fc1b[h] : 0.f;
            #pragma unroll
            for (int r = 0; r < 4; ++r) {
                float v = fmaxf(acc[nt][r] + bias, 0.f);
                int row = w * 16 + g * 4 + r;
                hid[row * 210 + h] = f2bfbits(v);
            }
        }
    } else {
        for (int i = tid; i < 128 * 200; i += 512) {
            int bb = i / 200, h = i - bb * 200;
            float s = fc1b[h];
            const unsigned short* prow = P + (size_t)(b0 + bb) * 1280;
            const unsigned short* wrow = W1 + (size_t)h * 1280;
            for (int j = 0; j < 1280; ++j)
                s += bfbits2f(prow[j]) * bfbits2f(wrow[j]);
            hid[bb * 210 + h] = f2bfbits(fmaxf(s, 0.f));
        }
    }
    __syncthreads();

    if (tid < 256) {
        int bb = tid >> 1, o = tid & 1;
        float s = fc2b[o];
        const unsigned short* hp = hid + bb * 210;
        const float* wp = fc2w + o * 200;
        #pragma unroll 8
        for (int j = 0; j < 200; ++j)
            s += bfbits2f(hp[j]) * wp[j];
        out[(size_t)(b0 + bb) * 2 + o] = 1.f / (1.f + __expf(-s));
    }
}

// ------------------------------------------------------------- launch ----
extern "C" void kernel_launch(void* const* d_in, const int* in_sizes, int n_in,
                              void* d_out, int out_size, void* d_ws, size_t ws_size,
                              hipStream_t stream)
{
    const float* x     = (const float*)d_in[0];
    const float* wq    = (const float*)d_in[1];
    const float* bq    = (const float*)d_in[2];
    const float* wk    = (const float*)d_in[3];
    // d_in[4] = bk: cancels under softmax row-invariance — unused.
    const float* wv    = (const float*)d_in[5];
    const float* bv    = (const float*)d_in[6];
    const float* rel_h = (const float*)d_in[7];
    const float* rel_w = (const float*)d_in[8];
    const float* gamma = (const float*)d_in[9];
    const float* beta  = (const float*)d_in[10];
    const float* mean  = (const float*)d_in[11];
    const float* var   = (const float*)d_in[12];
    const float* fc1w  = (const float*)d_in[13];
    const float* fc1b  = (const float*)d_in[14];
    const float* fc2w  = (const float*)d_in[15];
    const float* fc2b  = (const float*)d_in[16];

    char* ws = (char*)d_ws;
    __hip_bfloat16* pooled = (__hip_bfloat16*)(ws + OFF_P);
    float* out = (float*)d_out;

    setup_kernel<<<1175, 256, 0, stream>>>(wq, bq, wk, rel_h, rel_w, wv,
                                           gamma, beta, mean, var, fc1w, ws);
    attn_kernel<<<2048, 256, 0, stream>>>(x, bv, ws, pooled);
    fc_kernel<<<256, 512, 0, stream>>>(pooled, ws, fc1b, fc2w, fc2b, out);
}

// Round 5
// 233.730 us; speedup vs baseline: 7.3228x; 1.2492x over previous
//
#include <hip/hip_runtime.h>
#include <hip/hip_bf16.h>

// Workspace byte offsets
#define OFF_G    0u        // bf16 [128][128]  GA[oc][ic] = sum_o wq[o,ic]*wk[o,oc]
#define OFF_WVT  32768u    // bf16 [128][128]  WA[oc][j] = wv[oc][j] * bns[oc]  (BN-folded)
#define OFF_RT   65536u    // f32  [128][12]   Rm[c][i]
#define OFF_BNS  71680u    // f32  [128]       (unused by attn now)
#define OFF_BNB  72192u    // f32  [128]       bias2 = bv*bns + beta - mean*bns
#define OFF_FLAG 72704u    // int: 1 if MFMA fragment-layout probe verified
#define OFF_W1   72768u    // bf16 [208][1280] fc1 weights, k = m*128+c order
#define OFF_P    605248u   // bf16 [32768][1280] pooled, k = m*128+c order

typedef __attribute__((ext_vector_type(8))) unsigned short ushort8_t;
typedef __attribute__((ext_vector_type(8))) __bf16 bf16x8;
typedef __attribute__((ext_vector_type(4))) float f32x4;

static __device__ __forceinline__ float bfbits2f(unsigned short u) {
    return __uint_as_float(((unsigned)u) << 16);
}
static __device__ __forceinline__ unsigned short f2bfbits(float f) {
    __hip_bfloat16 h = __float2bfloat16(f);
    return *(unsigned short*)&h;
}
static __device__ __forceinline__ unsigned pack2bf(float a, float b) {
    return (unsigned)f2bfbits(a) | ((unsigned)f2bfbits(b) << 16);
}
static __device__ __forceinline__ f32x4 mfma16x16x32(ushort8_t a, ushort8_t b, f32x4 c) {
    return __builtin_amdgcn_mfma_f32_16x16x32_bf16(
        __builtin_bit_cast(bf16x8, a), __builtin_bit_cast(bf16x8, b), c, 0, 0, 0);
}

// ---------------------------------------------------------------- setup ----
__global__ void setup_kernel(const float* __restrict__ wq, const float* __restrict__ bq,
                             const float* __restrict__ wk,
                             const float* __restrict__ rel_h, const float* __restrict__ rel_w,
                             const float* __restrict__ wv, const float* __restrict__ bvp,
                             const float* __restrict__ gamma, const float* __restrict__ beta,
                             const float* __restrict__ mean, const float* __restrict__ var,
                             const float* __restrict__ fc1w,
                             char* __restrict__ ws)
{
    __hip_bfloat16* GA  = (__hip_bfloat16*)(ws + OFF_G);
    __hip_bfloat16* WA  = (__hip_bfloat16*)(ws + OFF_WVT);
    float*          Rm  = (float*)(ws + OFF_RT);
    float*          BnS = (float*)(ws + OFF_BNS);
    float*          Bi2 = (float*)(ws + OFF_BNB);
    __hip_bfloat16* W1  = (__hip_bfloat16*)(ws + OFF_W1);

    int idx = blockIdx.x * blockDim.x + threadIdx.x;
    if (idx < 16384) {
        int c = idx >> 7, a = idx & 127;     // GA[c][a] = sum_o wq[o,a]*wk[o,c]
        float s = 0.f;
        for (int o = 0; o < 128; ++o) s += wq[o * 128 + a] * wk[o * 128 + c];
        GA[idx] = __float2bfloat16(s);
    } else if (idx < 32768) {
        int t = idx - 16384;                 // WA[oc][j] = wv[oc][j] * inv[oc]
        int oc = t >> 7;
        float inv = gamma[oc] * rsqrtf(var[oc] + 1e-5f);
        WA[t] = __float2bfloat16(wv[t] * inv);
    } else if (idx < 34304) {
        int t = idx - 32768;                 // Rm[c][i]
        int c = t / 12, i = t - c * 12;
        float s = 0.f;
        for (int o = 0; o < 128; ++o)
            s += bq[o] * wk[o * 128 + c] + wq[o * 128 + c] * (rel_h[o * 12 + i] + rel_w[o]);
        Rm[t] = s;
    } else if (idx < 34432) {
        int c = idx - 34304;
        float inv = gamma[c] * rsqrtf(var[c] + 1e-5f);
        BnS[c] = inv;
        Bi2[c] = bvp[c] * inv + beta[c] - mean[c] * inv;
    } else if (idx < 300672) {
        int t = idx - 34432;                 // W1[h][m*128+c] = fc1w[h][c*10+m]
        int h = t / 1280, k = t - h * 1280;
        int m = k >> 7, c = k & 127;
        W1[t] = (h < 200) ? __float2bfloat16(fc1w[h * 1280 + c * 10 + m])
                          : __float2bfloat16(0.f);
    } else if (idx < 300736) {
        // ---- MFMA fragment-layout probe (one full wave) ----
        int l = idx - 300672;
        int m = l & 15, g = l >> 4;
        ushort8_t av, bv8;
        for (int j = 0; j < 8; ++j) {
            int k = g * 8 + j;
            float aval = (float)(((m * 5 + k * 3) % 7) - 3);
            float bval = (float)(((k * 11 + m * 2) % 5) - 2);
            av[j]  = (unsigned short)(__float_as_uint(aval) >> 16);
            bv8[j] = (unsigned short)(__float_as_uint(bval) >> 16);
        }
        f32x4 zero = {0.f, 0.f, 0.f, 0.f};
        f32x4 d = mfma16x16x32(av, bv8, zero);
        bool ok = true;
        int col = l & 15;
        for (int r = 0; r < 4; ++r) {
            int row = g * 4 + r;
            float ref = 0.f;
            for (int k = 0; k < 32; ++k)
                ref += (float)(((row * 5 + k * 3) % 7) - 3) *
                       (float)(((k * 11 + col * 2) % 5) - 2);
            if (d[r] != ref) ok = false;
        }
        unsigned long long ball = __ballot(ok ? 1 : 0);
        if (l == 0) *(int*)(ws + OFF_FLAG) = (ball == ~0ull) ? 1 : 0;
    }
}

// ------------------------------------------------- MFMA attention stage ----
// 256 thr = 4 waves, 4 batches/group, 4 groups/block. Pipeline per group:
//   [Xb write] bar [s1: t'=G^T X+R -> TZ] bar [s2: S=t'^T X, softmax -> PP]
//   bar [s2b: Y=Wv' X -> TZ space] bar [s3: out^T=P.Y^T + bias2, reg-pool,
//   direct global store].  out = Wv(X P^T) == (Wv X) P^T, BN folded into Wv.
// LDS 40960 B -> 4 blocks/CU (16 waves/CU); 4 barriers/iter.
// n-tiles are 16-aligned per batch (n = bb*16 + i, i in [0,12), rows 12-15
// zero) so every MFMA tile touches exactly one batch.
#define XB_H   0        // Xb  [64][128] u16, chunk-XOR swizzled (X^T per batch)
#define TZY_H  8192     // u16: t' [64][128] swizzled; after bar3: Y [4][128][16]
#define PP_H   16384    // u16: P [4][16][16] (row m, col n; zero-padded)
#define RM_F   8704     // f32 idx: Rm [128][12] (byte 34816; ends 40960)

__launch_bounds__(256, 4)
__global__ void attn_kernel(const float* __restrict__ x,
                            const char* __restrict__ ws,
                            __hip_bfloat16* __restrict__ pooled)
{
    __shared__ __align__(16) char lds[40960];
    unsigned short* LH = (unsigned short*)lds;
    float* RmL = (float*)lds + RM_F;

    const int tid = threadIdx.x;
    const int w = tid >> 6, l = tid & 63, g = l >> 4, lr = l & 15;

    const unsigned short* GA = (const unsigned short*)(ws + OFF_G);
    const unsigned short* WA = (const unsigned short*)(ws + OFF_WVT);
    const float* Rm  = (const float*)(ws + OFF_RT);
    const float* Bi2 = (const float*)(ws + OFF_BNB);

    // persistent per-wave weight fragments + per-lane bias
    ushort8_t gfrag[2][4], wfrag[2][4];
    float bias2v[2];
    #pragma unroll
    for (int mi = 0; mi < 2; ++mi) {
        int mt = w + mi * 4;
        #pragma unroll
        for (int kt = 0; kt < 4; ++kt) {
            gfrag[mi][kt] = *(const ushort8_t*)(GA + (mt * 16 + lr) * 128 + kt * 32 + g * 8);
            wfrag[mi][kt] = *(const ushort8_t*)(WA + (mt * 16 + lr) * 128 + kt * 32 + g * 8);
        }
        bias2v[mi] = Bi2[mt * 16 + lr];
    }
    for (int i = tid; i < 1536; i += 256) RmL[i] = Rm[i];

    const ushort8_t zero8 = {0, 0, 0, 0, 0, 0, 0, 0};
    // zero the pad rows (n = bb*16 + 12..15) of Xb once
    {
        int rr = tid >> 4, bb = rr >> 2, sub = rr & 3;
        int n = bb * 16 + 12 + sub;
        *(ushort8_t*)(LH + XB_H + n * 128 + (tid & 15) * 8) = zero8;
    }

    for (int grp = 0; grp < 4; ++grp) {
        const int b0g = blockIdx.x * 16 + grp * 4;

        // ---- load X -> Xb (swizzled X^T rows n=bb*16+i)
        {
            const int c = tid & 127, bh = tid >> 7;
            #pragma unroll
            for (int b2 = 0; b2 < 2; ++b2) {
                int bl = bh * 2 + b2;
                const float4* xp = (const float4*)(x + ((size_t)(b0g + bl) * 128 + c) * 12);
                float4 xa = xp[0], xb4 = xp[1], xc4 = xp[2];
                float xv[12] = {xa.x, xa.y, xa.z, xa.w, xb4.x, xb4.y, xb4.z, xb4.w,
                                xc4.x, xc4.y, xc4.z, xc4.w};
                #pragma unroll
                for (int i = 0; i < 12; ++i) {
                    int n = bl * 16 + i;
                    LH[XB_H + n * 128 + (((c >> 3) ^ i) << 3) + (c & 7)] = f2bfbits(xv[i]);
                }
            }
        }
        __syncthreads();   // bar1: Xb ready (also: prev s3 TZY/PP reads done)

        // ---- s1: t' = G^T X + R  -> TZ (transposed [n][c], swizzled)
        #pragma unroll
        for (int nt = 0; nt < 4; ++nt) {
            int n = nt * 16 + lr;
            ushort8_t bf[4];
            #pragma unroll
            for (int kt = 0; kt < 4; ++kt)
                bf[kt] = *(const ushort8_t*)(LH + XB_H + n * 128 + ((((kt << 2) + g) ^ lr) << 3));
            #pragma unroll
            for (int mi = 0; mi < 2; ++mi) {
                f32x4 acc = {0.f, 0.f, 0.f, 0.f};
                #pragma unroll
                for (int kt = 0; kt < 4; ++kt) acc = mfma16x16x32(gfrag[mi][kt], bf[kt], acc);
                int ocb = (w + mi * 4) * 16 + g * 4;
                float v0 = acc[0], v1 = acc[1], v2 = acc[2], v3 = acc[3];
                if (lr < 12) {
                    v0 += RmL[(ocb + 0) * 12 + lr];
                    v1 += RmL[(ocb + 1) * 12 + lr];
                    v2 += RmL[(ocb + 2) * 12 + lr];
                    v3 += RmL[(ocb + 3) * 12 + lr];
                }
                unsigned off = TZY_H + n * 128 + (((ocb >> 3) ^ lr) << 3) + ((g & 1) << 2);
                *(unsigned*)(LH + off)     = pack2bf(v0, v1);
                *(unsigned*)(LH + off + 2) = pack2bf(v2, v3);
            }
        }
        __syncthreads();   // bar2: t' ready

        // ---- s2: S = t'^T X (wave's own batch), softmax rows -> PP[m][n]
        {
            int n = w * 16 + lr;
            f32x4 s = {0.f, 0.f, 0.f, 0.f};
            #pragma unroll
            for (int kt = 0; kt < 4; ++kt) {
                unsigned ch = (((kt << 2) + g) ^ lr) << 3;
                ushort8_t af = *(const ushort8_t*)(LH + TZY_H + n * 128 + ch);
                ushort8_t bf = *(const ushort8_t*)(LH + XB_H + n * 128 + ch);
                s = mfma16x16x32(af, bf, s);
            }
            bool jv = (lr < 12);
            float mx[4], ev[4], sum[4];
            #pragma unroll
            for (int r = 0; r < 4; ++r) mx[r] = jv ? s[r] : -3.0e38f;
            #pragma unroll
            for (int d = 1; d < 16; d <<= 1) {
                #pragma unroll
                for (int r = 0; r < 4; ++r) mx[r] = fmaxf(mx[r], __shfl_xor(mx[r], d));
            }
            #pragma unroll
            for (int r = 0; r < 4; ++r) { ev[r] = jv ? __expf(s[r] - mx[r]) : 0.f; sum[r] = ev[r]; }
            #pragma unroll
            for (int d = 1; d < 16; d <<= 1) {
                #pragma unroll
                for (int r = 0; r < 4; ++r) sum[r] += __shfl_xor(sum[r], d);
            }
            #pragma unroll
            for (int r = 0; r < 4; ++r)
                LH[PP_H + w * 256 + (g * 4 + r) * 16 + lr] = f2bfbits(ev[r] / sum[r]);
        }
        __syncthreads();   // bar3: t' reads done -> TZ space reusable as Y

        // ---- s2b: Y = Wv' X  -> Y[bb][oc][i] (over TZ space)
        #pragma unroll
        for (int nt = 0; nt < 4; ++nt) {
            int n = nt * 16 + lr;
            ushort8_t bf[4];
            #pragma unroll
            for (int kt = 0; kt < 4; ++kt)
                bf[kt] = *(const ushort8_t*)(LH + XB_H + n * 128 + ((((kt << 2) + g) ^ lr) << 3));
            #pragma unroll
            for (int mi = 0; mi < 2; ++mi) {
                f32x4 acc = {0.f, 0.f, 0.f, 0.f};
                #pragma unroll
                for (int kt = 0; kt < 4; ++kt) acc = mfma16x16x32(wfrag[mi][kt], bf[kt], acc);
                int ocb = (w + mi * 4) * 16 + g * 4;
                #pragma unroll
                for (int r = 0; r < 4; ++r)
                    LH[TZY_H + nt * 2048 + (ocb + r) * 16 + lr] = f2bfbits(acc[r]);
            }
        }
        __syncthreads();   // bar4: Y + PP ready

        // ---- s3: out^T = P . Y^T + bias2; ReLU; pool(3) in regs; store
        #pragma unroll
        for (int mi = 0; mi < 2; ++mi) {
            int mt = w + mi * 4;
            float bias = bias2v[mi];
            #pragma unroll
            for (int bb = 0; bb < 4; ++bb) {
                ushort8_t af = (g < 2)
                    ? *(const ushort8_t*)(LH + PP_H + bb * 256 + lr * 16 + g * 8) : zero8;
                ushort8_t bfy = (g < 2)
                    ? *(const ushort8_t*)(LH + TZY_H + bb * 2048 + (mt * 16 + lr) * 16 + g * 8)
                    : zero8;
                f32x4 o = {bias, bias, bias, bias};
                o = mfma16x16x32(af, bfy, o);
                float s0 = __shfl_down(o[0], 16);
                float s1 = __shfl_down(o[1], 16);
                float p0 = fmaxf(fmaxf(o[0], o[1]), o[2]);
                float p1 = fmaxf(fmaxf(o[1], o[2]), o[3]);
                float p2 = fmaxf(fmaxf(o[2], o[3]), s0);
                float p3 = fmaxf(fmaxf(o[3], s0), s1);
                unsigned short* pb = (unsigned short*)pooled
                                   + (size_t)(b0g + bb) * 1280 + mt * 16 + lr;
                if (g < 3) pb[(g * 4 + 0) * 128] = f2bfbits(fmaxf(p0, 0.f));
                if (g < 3) pb[(g * 4 + 1) * 128] = f2bfbits(fmaxf(p1, 0.f));
                if (g < 2) pb[(g * 4 + 2) * 128] = f2bfbits(fmaxf(p2, 0.f));
                if (g < 2) pb[(g * 4 + 3) * 128] = f2bfbits(fmaxf(p3, 0.f));
            }
        }
        // no end barrier: next iter's Xb write targets a region no one reads
        // after bar4, and bar1 orders it against s1's TZ overwrite.
    }
}

// ----------------------------------------------------------- fc1+fc2 ----
__launch_bounds__(512, 1)
__global__ void fc_kernel(const __hip_bfloat16* __restrict__ pooled_bf,
                          const char* __restrict__ ws,
                          const float* __restrict__ fc1b,
                          const float* __restrict__ fc2w, const float* __restrict__ fc2b,
                          float* __restrict__ out)
{
    __shared__ char smem[54272];
    const int tid = threadIdx.x;
    const int b0  = blockIdx.x * 128;
    const unsigned short* P  = (const unsigned short*)pooled_bf;
    const unsigned short* W1 = (const unsigned short*)(ws + OFF_W1);
    unsigned short* hid = (unsigned short*)smem;
    const int flag = *(const int*)(ws + OFF_FLAG);

    if (flag) {
        const int l = tid & 63, w = tid >> 6;
        const int lrow = l & 15, g = l >> 4;
        f32x4 acc[13];
        #pragma unroll
        for (int nt = 0; nt < 13; ++nt) acc[nt] = (f32x4){0.f, 0.f, 0.f, 0.f};

        const int pr = tid >> 2, pc = tid & 3;
        const size_t pbase = (size_t)(b0 + pr) * 1280 + pc * 8;
        const int i1 = tid, i2 = tid + 512;
        const int h1 = i1 >> 2, c1 = i1 & 3;
        const int h2 = i2 >> 2, c2 = i2 & 3;
        const bool has2 = (i2 < 832);

        ushort8_t pReg, w1a, w1b;
        pReg = *(const ushort8_t*)(P + pbase);
        w1a  = *(const ushort8_t*)(W1 + (size_t)h1 * 1280 + c1 * 8);
        if (has2) w1b = *(const ushort8_t*)(W1 + (size_t)h2 * 1280 + c2 * 8);
        *(ushort8_t*)(smem + tid * 16) = pReg;
        *(ushort8_t*)(smem + 8192 + i1 * 16) = w1a;
        if (has2) *(ushort8_t*)(smem + 8192 + i2 * 16) = w1b;
        __syncthreads();

        int cur = 0;
        for (int ks = 0; ks < 40; ++ks) {
            if (ks + 1 < 40) {
                pReg = *(const ushort8_t*)(P + pbase + (size_t)(ks + 1) * 32);
                w1a  = *(const ushort8_t*)(W1 + (size_t)h1 * 1280 + (ks + 1) * 32 + c1 * 8);
                if (has2) w1b = *(const ushort8_t*)(W1 + (size_t)h2 * 1280 + (ks + 1) * 32 + c2 * 8);
            }
            const unsigned short* Pt = (const unsigned short*)(smem + (cur ? 21504 : 0));
            const unsigned short* Wt = (const unsigned short*)(smem + (cur ? 29696 : 8192));
            ushort8_t A = *(const ushort8_t*)(Pt + (w * 16 + lrow) * 32 + g * 8);
            #pragma unroll
            for (int nt = 0; nt < 13; ++nt) {
                ushort8_t Bf = *(const ushort8_t*)(Wt + (nt * 16 + lrow) * 32 + g * 8);
                acc[nt] = mfma16x16x32(A, Bf, acc[nt]);
            }
            __syncthreads();
            if (ks + 1 < 40) {
                char* dp = smem + ((cur ^ 1) ? 21504 : 0);
                char* dw = smem + ((cur ^ 1) ? 29696 : 8192);
                *(ushort8_t*)(dp + tid * 16) = pReg;
                *(ushort8_t*)(dw + i1 * 16) = w1a;
                if (has2) *(ushort8_t*)(dw + i2 * 16) = w1b;
            }
            __syncthreads();
            cur ^= 1;
        }
        #pragma unroll
        for (int nt = 0; nt < 13; ++nt) {
            int h = nt * 16 + lrow;
            float bias = (h < 200) ? fc1b[h] : 0.f;
            #pragma unroll
            for (int r = 0; r < 4; ++r) {
                float v = fmaxf(acc[nt][r] + bias, 0.f);
                int row = w * 16 + g * 4 + r;
                hid[row * 210 + h] = f2bfbits(v);
            }
        }
    } else {
        for (int i = tid; i < 128 * 200; i += 512) {
            int bb = i / 200, h = i - bb * 200;
            float s = fc1b[h];
            const unsigned short* prow = P + (size_t)(b0 + bb) * 1280;
            const unsigned short* wrow = W1 + (size_t)h * 1280;
            for (int j = 0; j < 1280; ++j)
                s += bfbits2f(prow[j]) * bfbits2f(wrow[j]);
            hid[bb * 210 + h] = f2bfbits(fmaxf(s, 0.f));
        }
    }
    __syncthreads();

    if (tid < 256) {
        int bb = tid >> 1, o = tid & 1;
        float s = fc2b[o];
        const unsigned short* hp = hid + bb * 210;
        const float* wp = fc2w + o * 200;
        #pragma unroll 8
        for (int j = 0; j < 200; ++j)
            s += bfbits2f(hp[j]) * wp[j];
        out[(size_t)(b0 + bb) * 2 + o] = 1.f / (1.f + __expf(-s));
    }
}

// ------------------------------------------------------------- launch ----
extern "C" void kernel_launch(void* const* d_in, const int* in_sizes, int n_in,
                              void* d_out, int out_size, void* d_ws, size_t ws_size,
                              hipStream_t stream)
{
    const float* x     = (const float*)d_in[0];
    const float* wq    = (const float*)d_in[1];
    const float* bq    = (const float*)d_in[2];
    const float* wk    = (const float*)d_in[3];
    // d_in[4] = bk: cancels under softmax row-invariance — unused.
    const float* wv    = (const float*)d_in[5];
    const float* bv    = (const float*)d_in[6];
    const float* rel_h = (const float*)d_in[7];
    const float* rel_w = (const float*)d_in[8];
    const float* gamma = (const float*)d_in[9];
    const float* beta  = (const float*)d_in[10];
    const float* mean  = (const float*)d_in[11];
    const float* var   = (const float*)d_in[12];
    const float* fc1w  = (const float*)d_in[13];
    const float* fc1b  = (const float*)d_in[14];
    const float* fc2w  = (const float*)d_in[15];
    const float* fc2b  = (const float*)d_in[16];

    char* ws = (char*)d_ws;
    __hip_bfloat16* pooled = (__hip_bfloat16*)(ws + OFF_P);
    float* out = (float*)d_out;

    setup_kernel<<<1175, 256, 0, stream>>>(wq, bq, wk, rel_h, rel_w, wv, bv,
                                           gamma, beta, mean, var, fc1w, ws);
    attn_kernel<<<2048, 256, 0, stream>>>(x, ws, pooled);
    fc_kernel<<<256, 512, 0, stream>>>(pooled, ws, fc1b, fc2w, fc2b, out);
}